// Round 12
// baseline (315.379 us; speedup 1.0000x reference)
//
#include <hip/hip_runtime.h>
#include <hip/hip_bf16.h>
#include <stdint.h>

#define D_MODEL 1024
#define D_INNER 2048
#define NEXP 8
#define TOPK 2
#define T256 40
#define T128 72

typedef float f32x4 __attribute__((ext_vector_type(4)));
typedef short bf16x8 __attribute__((ext_vector_type(8)));

#define MEMFENCE asm volatile("" ::: "memory")
#define SB __builtin_amdgcn_sched_barrier(0)
#define LGKM0 asm volatile("s_waitcnt lgkmcnt(0)" ::: "memory")
#define VM0 asm volatile("s_waitcnt vmcnt(0)" ::: "memory")
#define VM6 asm volatile("s_waitcnt vmcnt(6)" ::: "memory")
#define BAR __builtin_amdgcn_s_barrier()

// 8-MFMA quadrant: ACC[I0..I0+1][J0..J0+1] += AF x BF (2 k-slices each)
#define Q8(I0, J0, AF, BF)                                                        \
  _Pragma("unroll") for (int i_ = 0; i_ < 2; i_++)                                \
    _Pragma("unroll") for (int j_ = 0; j_ < 2; j_++) {                            \
      acc[(I0) + i_][(J0) + j_] = __builtin_amdgcn_mfma_f32_16x16x32_bf16(        \
          AF[2 * i_], BF[2 * j_], acc[(I0) + i_][(J0) + j_], 0, 0, 0);            \
      acc[(I0) + i_][(J0) + j_] = __builtin_amdgcn_mfma_f32_16x16x32_bf16(        \
          AF[2 * i_ + 1], BF[2 * j_ + 1], acc[(I0) + i_][(J0) + j_], 0, 0, 0);    \
    }

__device__ __forceinline__ unsigned short f2b(float f) {
    union { float f; uint32_t u; } v; v.f = f;
    uint32_t u = v.u;
    return (unsigned short)((u + 0x7fffu + ((u >> 16) & 1u)) >> 16);
}

__device__ __forceinline__ void gl_lds16(const void* g, void* l) {
    __builtin_amdgcn_global_load_lds((const __attribute__((address_space(1))) void*)g,
                                     (__attribute__((address_space(3))) void*)l, 16, 0, 0);
}

// ------- cast+transpose all 3 weights: [E][K][N] fp32 -> [E][N][K] bf16 -------
__global__ __launch_bounds__(256) void tcast3_kernel(
    const float* __restrict__ gw, const float* __restrict__ uw, const float* __restrict__ dw,
    unsigned short* __restrict__ gT, unsigned short* __restrict__ uT, unsigned short* __restrict__ dT)
{
    __shared__ unsigned short S[64][68];
    int which = blockIdx.z >> 3;
    int e = blockIdx.z & 7;
    const float* in; unsigned short* out; int K, N;
    if (which == 0)      { in = gw; out = gT; K = D_MODEL; N = D_INNER; }
    else if (which == 1) { in = uw; out = uT; K = D_MODEL; N = D_INNER; }
    else                 { in = dw; out = dT; K = D_INNER; N = D_MODEL; }
    int n0 = blockIdx.x * 64, k0 = blockIdx.y * 64;
    if (n0 >= N || k0 >= K) return;
    const float* ib = in + (size_t)e * K * N;
    unsigned short* ob = out + (size_t)e * N * K;
    int tid = threadIdx.x;
    int kk = tid >> 4, nn4 = (tid & 15) * 4;
#pragma unroll
    for (int j = 0; j < 4; j++) {
        int k = kk + 16 * j;
        float4 v = *(const float4*)&ib[(size_t)(k0 + k) * N + n0 + nn4];
        ushort4 s; s.x = f2b(v.x); s.y = f2b(v.y); s.z = f2b(v.z); s.w = f2b(v.w);
        *(ushort4*)&S[k][nn4] = s;
    }
    __syncthreads();
    int nn = tid >> 4, kk4 = (tid & 15) * 4;
#pragma unroll
    for (int j = 0; j < 4; j++) {
        int n = nn + 16 * j;
        ushort4 s;
        s.x = S[kk4 + 0][n]; s.y = S[kk4 + 1][n];
        s.z = S[kk4 + 2][n]; s.w = S[kk4 + 3][n];
        *(ushort4*)&ob[(size_t)(n0 + n) * K + k0 + kk4] = s;
    }
}

// ---------------- router (+ fused x->bf16 cast): 1 wave per token ----------------
__global__ __launch_bounds__(64) void router_kernel(
    const float* __restrict__ x, const float* __restrict__ rw,
    const float* __restrict__ rb, unsigned short* __restrict__ xb,
    int* __restrict__ top_i, float* __restrict__ top_w, int T)
{
    int t = blockIdx.x;
    if (t >= T) return;
    int l = threadIdx.x;
    float xv[16];
#pragma unroll
    for (int i = 0; i < 16; i++) xv[i] = x[(size_t)t * D_MODEL + l + 64 * i];
#pragma unroll
    for (int i = 0; i < 16; i++) xb[(size_t)t * D_MODEL + l + 64 * i] = f2b(xv[i]);
    float logit[NEXP];
#pragma unroll
    for (int e = 0; e < NEXP; e++) {
        float acc = 0.f;
#pragma unroll
        for (int i = 0; i < 16; i++) acc += xv[i] * rw[e * D_MODEL + l + 64 * i];
#pragma unroll
        for (int s = 32; s > 0; s >>= 1) acc += __shfl_xor(acc, s, 64);
        logit[e] = acc + rb[e];
    }
    if (l == 0) {
        int i0 = 0; float m0 = logit[0];
#pragma unroll
        for (int e = 1; e < NEXP; e++) if (logit[e] > m0) { m0 = logit[e]; i0 = e; }
        int i1 = -1; float m1 = -3.0e38f;
#pragma unroll
        for (int e = 0; e < NEXP; e++) {
            if (e == i0) continue;
            if (logit[e] > m1) { m1 = logit[e]; i1 = e; }
        }
        float w0 = 1.f / (1.f + expf(m1 - m0));
        top_i[t * 2 + 0] = i0; top_i[t * 2 + 1] = i1;
        top_w[t * 2 + 0] = w0; top_w[t * 2 + 1] = 1.f - w0;
    }
}

// ---------------- bucket build + compact tile worklists ----------------
__global__ __launch_bounds__(256) void bucket_kernel(
    const int* __restrict__ top_i, const float* __restrict__ top_w,
    int* __restrict__ meta, int* __restrict__ tok_of_slot,
    float* __restrict__ w_of_slot, int T)
{
    __shared__ int cnt[256][NEXP];
    __shared__ int pre[256][NEXP];
    __shared__ int tot[NEXP];
    __shared__ int off[NEXP + 1];
    int tid = threadIdx.x;
    int per = (T + 255) / 256;
    int t0 = tid * per;
    for (int e = 0; e < NEXP; e++) cnt[tid][e] = 0;
    for (int t = t0; t < t0 + per && t < T; t++)
        for (int k = 0; k < TOPK; k++) cnt[tid][top_i[t * 2 + k]]++;
    __syncthreads();
    if (tid < NEXP) {
        int run = 0;
        for (int i = 0; i < 256; i++) { pre[i][tid] = run; run += cnt[i][tid]; }
        tot[tid] = run;
    }
    __syncthreads();
    if (tid == 0) {
        off[0] = 0;
        for (int e = 0; e < NEXP; e++) off[e + 1] = off[e] + tot[e];
        for (int e = 0; e <= NEXP; e++) meta[e] = off[e];
        int nt = 0;
        for (int e = 0; e < NEXP; e++)
            for (int r = off[e]; r < off[e + 1]; r += 256)
                meta[16 + nt++] = (e << 16) | r;
        meta[11] = nt;
        for (; nt < T256; nt++) meta[16 + nt] = -1;
        nt = 0;
        for (int e = 0; e < NEXP; e++)
            for (int r = off[e]; r < off[e + 1]; r += 128)
                meta[64 + nt++] = (e << 16) | r;
        meta[12] = nt;
        for (; nt < T128; nt++) meta[64 + nt] = -1;
    }
    __syncthreads();
    int lc[NEXP];
#pragma unroll
    for (int e = 0; e < NEXP; e++) lc[e] = 0;
    for (int t = t0; t < t0 + per && t < T; t++) {
        for (int k = 0; k < TOPK; k++) {
            int e = top_i[t * 2 + k];
            int slot = off[e] + pre[tid][e] + lc[e]++;
            tok_of_slot[slot] = t;
            w_of_slot[slot] = top_w[t * 2 + k];
        }
    }
}

// ======================= gate+up GEMM + swiglu -> H =======================
// 512 thr / 8 waves (4M x 2sel). Tile M=256 x F=64 with Bg,Bu stacked; per-wave
// 64x64 of ONE matrix (acc=64). BK=64, 3-ring x 48KB LDS (144KB, 1 blk/CU).
// 4 quadrant phases/K-tile {ds_read + 2 stage -> BAR -> lgkm0 -> 8 MFMA -> BAR},
// counted vmcnt(6) at P3 only (2-deep prefetch).
__global__ __launch_bounds__(512, 2) void moe_gate_up(
    const unsigned short* __restrict__ xb, const unsigned short* __restrict__ wgT,
    const unsigned short* __restrict__ wuT, const int* __restrict__ meta,
    const int* __restrict__ tok_of_slot, unsigned short* __restrict__ H)
{
    extern __shared__ __align__(16) unsigned short lds[];   // 3 * 24576 ushorts

    int lin = blockIdx.x;
    int strip = (lin & 7) * 4 + ((lin >> 3) & 3);   // lin%8 = XCD
    int tix = lin >> 5;
    int packed = meta[16 + tix];
    if (packed < 0) return;
    int e = packed >> 16, row0 = packed & 0xffff;
    int Mloc = min(256, meta[e + 1] - row0);
    int f0 = strip * 64;

    int tid = threadIdx.x, wv = tid >> 6, lane = tid & 63;
    int lrow = lane & 15, kgrp = lane >> 4, sw = lrow & 7;
    int mh = wv >> 1, sel = wv & 1;
    int co0 = 8 * (kgrp ^ sw);
    int co1 = 8 * ((4 + kgrp) ^ sw);

    // staging (per thread per K-tile: 4 A-sweeps + G + U = 6 gl_lds block-wide,
    // each sweep 8KB = 64 rows x 64 k)
    int srow = tid >> 3, schk = tid & 7;
    const unsigned short* sA[4];
#pragma unroll
    for (int j = 0; j < 4; j++) {
        int r = j * 64 + srow;
        int slot = row0 + ((r < Mloc) ? r : 0);
        sA[j] = xb + (size_t)tok_of_slot[slot] * D_MODEL + 8 * (schk ^ (r & 7));
    }
    const unsigned short *sG, *sU;
    {
        size_t wb = (size_t)e * D_MODEL * D_INNER + (size_t)(f0 + srow) * D_MODEL + 8 * (schk ^ (srow & 7));
        sG = wgT + wb; sU = wuT + wb;
    }
    int dst = tid * 8;

    int aoff[4], boff[4];
#pragma unroll
    for (int i = 0; i < 4; i++) aoff[i] = (mh * 64 + i * 16 + lrow) * 64;
    int bb = 16384 + sel * 4096;
#pragma unroll
    for (int i = 0; i < 4; i++) boff[i] = bb + (i * 16 + lrow) * 64;

    f32x4 acc[4][4];
#pragma unroll
    for (int i = 0; i < 4; i++)
#pragma unroll
        for (int j = 0; j < 4; j++) acc[i][j] = (f32x4){0.f, 0.f, 0.f, 0.f};

    auto stageA01 = [&](int u) {
        int kk = u * 64; unsigned short* b = lds + (u % 3) * 24576;
        gl_lds16(sA[0] + kk, b + dst);
        gl_lds16(sA[1] + kk, b + 4096 + dst);
    };
    auto stageA23 = [&](int u) {
        int kk = u * 64; unsigned short* b = lds + (u % 3) * 24576;
        gl_lds16(sA[2] + kk, b + 8192 + dst);
        gl_lds16(sA[3] + kk, b + 12288 + dst);
    };
    auto stageGU = [&](int u) {
        int kk = u * 64; unsigned short* b = lds + (u % 3) * 24576;
        gl_lds16(sG + kk, b + 16384 + dst);
        gl_lds16(sU + kk, b + 20480 + dst);
    };

    bf16x8 A0[4], A1[4], B0[4], B1[4];

    const int NT = D_MODEL / 64;   // 16
    stageA01(0); stageA23(0); stageGU(0);
    stageA01(1); stageA23(1); stageGU(1);
    MEMFENCE; VM6; BAR; MEMFENCE;

    for (int t = 0; t < NT; ++t) {
        const unsigned short* b = lds + (t % 3) * 24576;
        bool pf = (t + 2) < NT;
        // ---- P0: read A0 + B0, stage A01(t+2), MFMA (A0,B0) ----
        A0[0] = *(const bf16x8*)(b + aoff[0] + co0);
        A0[1] = *(const bf16x8*)(b + aoff[0] + co1);
        A0[2] = *(const bf16x8*)(b + aoff[1] + co0);
        A0[3] = *(const bf16x8*)(b + aoff[1] + co1);
        B0[0] = *(const bf16x8*)(b + boff[0] + co0);
        B0[1] = *(const bf16x8*)(b + boff[0] + co1);
        B0[2] = *(const bf16x8*)(b + boff[1] + co0);
        B0[3] = *(const bf16x8*)(b + boff[1] + co1);
        if (pf) stageA01(t + 2);
        SB; BAR; LGKM0; SB;
        __builtin_amdgcn_s_setprio(1); Q8(0, 0, A0, B0); __builtin_amdgcn_s_setprio(0);
        SB; BAR;
        // ---- P1: read B1, stage A23(t+2), MFMA (A0,B1) ----
        B1[0] = *(const bf16x8*)(b + boff[2] + co0);
        B1[1] = *(const bf16x8*)(b + boff[2] + co1);
        B1[2] = *(const bf16x8*)(b + boff[3] + co0);
        B1[3] = *(const bf16x8*)(b + boff[3] + co1);
        if (pf) stageA23(t + 2);
        SB; BAR; LGKM0; SB;
        __builtin_amdgcn_s_setprio(1); Q8(0, 2, A0, B1); __builtin_amdgcn_s_setprio(0);
        SB; BAR;
        // ---- P2: read A1, stage GU(t+2), MFMA (A1,B0) ----
        A1[0] = *(const bf16x8*)(b + aoff[2] + co0);
        A1[1] = *(const bf16x8*)(b + aoff[2] + co1);
        A1[2] = *(const bf16x8*)(b + aoff[3] + co0);
        A1[3] = *(const bf16x8*)(b + aoff[3] + co1);
        if (pf) stageGU(t + 2);
        SB; BAR; LGKM0; SB;
        __builtin_amdgcn_s_setprio(1); Q8(2, 0, A1, B0); __builtin_amdgcn_s_setprio(0);
        SB; BAR;
        // ---- P3: MFMA (A1,B1), counted vmcnt ----
        __builtin_amdgcn_s_setprio(1); Q8(2, 2, A1, B1); __builtin_amdgcn_s_setprio(0);
        SB;
        if (pf) { VM6; } else { VM0; }   // t+1 landed; t+2 stays in flight
        BAR; MEMFENCE;
    }

    // epilogue: u-waves publish acc via LDS f32 [64][65] per mh; g-waves fuse silu
    __syncthreads();
    float* ex = (float*)lds;
    if (sel == 1) {
        float* d = ex + mh * 4160;
#pragma unroll
        for (int i = 0; i < 4; i++)
#pragma unroll
            for (int j = 0; j < 4; j++)
#pragma unroll
                for (int r = 0; r < 4; r++)
                    d[(i * 16 + kgrp * 4 + r) * 65 + j * 16 + lrow] = acc[i][j][r];
    }
    __syncthreads();
    if (sel == 0) {
        const float* s = ex + mh * 4160;
#pragma unroll
        for (int i = 0; i < 4; i++)
#pragma unroll
            for (int j = 0; j < 4; j++)
#pragma unroll
                for (int r = 0; r < 4; r++) {
                    int row = i * 16 + kgrp * 4 + r;
                    int m = mh * 64 + row;
                    if (m < Mloc) {
                        float g = acc[i][j][r];
                        float u = s[row * 65 + j * 16 + lrow];
                        float h = g / (1.f + __expf(-g)) * u;
                        H[(size_t)(row0 + m) * D_INNER + f0 + j * 16 + lrow] = f2b(h);
                    }
                }
    }
}

// ======================= down GEMM + weighted scatter =======================
// 512 thr / 8 waves (2M x 4N). Tile M=128 x N=256, BK=64, K split in halves
// (kq) -> 576 blocks. 3-ring x 48KB LDS, same 4-phase quadrant schedule.
__global__ __launch_bounds__(512, 2) void moe_down(
    const unsigned short* __restrict__ H, const unsigned short* __restrict__ wdT,
    const int* __restrict__ meta, const int* __restrict__ tok_of_slot,
    const float* __restrict__ w_of_slot, float* __restrict__ out, int S2)
{
    extern __shared__ __align__(16) unsigned short lds[];   // 3 * 24576 ushorts
    __shared__ int toks[128];
    __shared__ float wts[128];

    int lin = blockIdx.x;
    int dstrip = lin & 3;
    int kq = (lin >> 2) & 1;
    int tix = lin >> 3;
    int packed = meta[64 + tix];
    if (packed < 0) return;
    int e = packed >> 16, row0 = packed & 0xffff;
    int Mloc = min(128, meta[e + 1] - row0);
    int d0 = dstrip * 256;
    int kb = kq * 1024;

    int tid = threadIdx.x, wv = tid >> 6, lane = tid & 63;
    int lrow = lane & 15, kgrp = lane >> 4, sw = lrow & 7;
    int mh = wv >> 2, nh = wv & 3;
    int co0 = 8 * (kgrp ^ sw);
    int co1 = 8 * ((4 + kgrp) ^ sw);

    if (tid < 128) {
        bool v = tid < Mloc;
        toks[tid] = v ? tok_of_slot[row0 + tid] : 0;
        wts[tid] = v ? w_of_slot[row0 + tid] : 0.f;
    }

    int srow = tid >> 3, schk = tid & 7;
    const unsigned short* sA[2];
#pragma unroll
    for (int j = 0; j < 2; j++) {
        int r = j * 64 + srow;
        int slot = min(row0 + r, S2 - 1);
        sA[j] = H + (size_t)slot * D_INNER + kb + 8 * (schk ^ (r & 7));
    }
    const unsigned short* sB[4];
#pragma unroll
    for (int j = 0; j < 4; j++) {
        int r = j * 64 + srow;
        sB[j] = wdT + (size_t)e * D_INNER * D_MODEL + (size_t)(d0 + r) * D_INNER + kb + 8 * (schk ^ (r & 7));
    }
    int dst = tid * 8;

    int aoff[4], boff[4];
#pragma unroll
    for (int i = 0; i < 4; i++) aoff[i] = (mh * 64 + i * 16 + lrow) * 64;
#pragma unroll
    for (int i = 0; i < 4; i++) boff[i] = 8192 + (nh * 64 + i * 16 + lrow) * 64;

    f32x4 acc[4][4];
#pragma unroll
    for (int i = 0; i < 4; i++)
#pragma unroll
        for (int j = 0; j < 4; j++) acc[i][j] = (f32x4){0.f, 0.f, 0.f, 0.f};

    auto stageA = [&](int u) {
        int kk = u * 64; unsigned short* b = lds + (u % 3) * 24576;
        gl_lds16(sA[0] + kk, b + dst);
        gl_lds16(sA[1] + kk, b + 4096 + dst);
    };
    auto stageB01 = [&](int u) {
        int kk = u * 64; unsigned short* b = lds + (u % 3) * 24576;
        gl_lds16(sB[0] + kk, b + 8192 + dst);
        gl_lds16(sB[1] + kk, b + 12288 + dst);
    };
    auto stageB23 = [&](int u) {
        int kk = u * 64; unsigned short* b = lds + (u % 3) * 24576;
        gl_lds16(sB[2] + kk, b + 16384 + dst);
        gl_lds16(sB[3] + kk, b + 20480 + dst);
    };

    bf16x8 A0[4], A1[4], B0[4], B1[4];

    const int NT = 1024 / 64;   // 16
    stageA(0); stageB01(0); stageB23(0);
    stageA(1); stageB01(1); stageB23(1);
    MEMFENCE; VM6; BAR; MEMFENCE;

    for (int t = 0; t < NT; ++t) {
        const unsigned short* b = lds + (t % 3) * 24576;
        bool pf = (t + 2) < NT;
        // ---- P0 ----
        A0[0] = *(const bf16x8*)(b + aoff[0] + co0);
        A0[1] = *(const bf16x8*)(b + aoff[0] + co1);
        A0[2] = *(const bf16x8*)(b + aoff[1] + co0);
        A0[3] = *(const bf16x8*)(b + aoff[1] + co1);
        B0[0] = *(const bf16x8*)(b + boff[0] + co0);
        B0[1] = *(const bf16x8*)(b + boff[0] + co1);
        B0[2] = *(const bf16x8*)(b + boff[1] + co0);
        B0[3] = *(const bf16x8*)(b + boff[1] + co1);
        if (pf) stageA(t + 2);
        SB; BAR; LGKM0; SB;
        __builtin_amdgcn_s_setprio(1); Q8(0, 0, A0, B0); __builtin_amdgcn_s_setprio(0);
        SB; BAR;
        // ---- P1 ----
        B1[0] = *(const bf16x8*)(b + boff[2] + co0);
        B1[1] = *(const bf16x8*)(b + boff[2] + co1);
        B1[2] = *(const bf16x8*)(b + boff[3] + co0);
        B1[3] = *(const bf16x8*)(b + boff[3] + co1);
        if (pf) stageB01(t + 2);
        SB; BAR; LGKM0; SB;
        __builtin_amdgcn_s_setprio(1); Q8(0, 2, A0, B1); __builtin_amdgcn_s_setprio(0);
        SB; BAR;
        // ---- P2 ----
        A1[0] = *(const bf16x8*)(b + aoff[2] + co0);
        A1[1] = *(const bf16x8*)(b + aoff[2] + co1);
        A1[2] = *(const bf16x8*)(b + aoff[3] + co0);
        A1[3] = *(const bf16x8*)(b + aoff[3] + co1);
        if (pf) stageB23(t + 2);
        SB; BAR; LGKM0; SB;
        __builtin_amdgcn_s_setprio(1); Q8(2, 0, A1, B0); __builtin_amdgcn_s_setprio(0);
        SB; BAR;
        // ---- P3 ----
        __builtin_amdgcn_s_setprio(1); Q8(2, 2, A1, B1); __builtin_amdgcn_s_setprio(0);
        SB;
        if (pf) { VM6; } else { VM0; }
        BAR; MEMFENCE;
    }

    // epilogue: weighted atomic scatter (4 commutative fp32 adds/elem total)
#pragma unroll
    for (int i = 0; i < 4; i++)
#pragma unroll
        for (int j = 0; j < 4; j++)
#pragma unroll
            for (int r = 0; r < 4; r++) {
                int m = mh * 64 + i * 16 + kgrp * 4 + r;
                if (m < Mloc) {
                    int n = d0 + nh * 64 + j * 16 + lrow;
                    atomicAdd(&out[(size_t)toks[m] * D_MODEL + n], wts[m] * acc[i][j][r]);
                }
            }
}

extern "C" void kernel_launch(void* const* d_in, const int* in_sizes, int n_in,
                              void* d_out, int out_size, void* d_ws, size_t ws_size,
                              hipStream_t stream) {
    const float* x  = (const float*)d_in[0];
    const float* rw = (const float*)d_in[1];
    const float* rb = (const float*)d_in[2];
    const float* gw = (const float*)d_in[3];
    const float* uw = (const float*)d_in[4];
    const float* dw = (const float*)d_in[5];
    float* out = (float*)d_out;

    int T = in_sizes[0] / D_MODEL;   // 4096
    int S2 = 2 * T;                   // 8192 slots

    char* ws = (char*)d_ws;
    size_t cur = 0;
    auto take = [&](size_t bytes) { char* p = ws + cur; cur = (cur + bytes + 255) & ~(size_t)255; return p; };
    int*   top_i = (int*)take((size_t)S2 * 4);
    float* top_w = (float*)take((size_t)S2 * 4);
    int*   meta  = (int*)take(1024);
    int*   tos   = (int*)take((size_t)S2 * 4);
    float* wos   = (float*)take((size_t)S2 * 4);
    unsigned short* xb  = (unsigned short*)take((size_t)T * D_MODEL * 2);
    unsigned short* wgT = (unsigned short*)take((size_t)NEXP * D_MODEL * D_INNER * 2);
    unsigned short* wuT = (unsigned short*)take((size_t)NEXP * D_MODEL * D_INNER * 2);
    unsigned short* wdT = (unsigned short*)take((size_t)NEXP * D_MODEL * D_INNER * 2);
    unsigned short* H   = (unsigned short*)take((size_t)S2 * D_INNER * 2);

    static const int RING_LDS = 3 * 24576 * 2;   // 147456 B
    hipFuncSetAttribute((const void*)moe_gate_up,
                        hipFuncAttributeMaxDynamicSharedMemorySize, RING_LDS);
    hipFuncSetAttribute((const void*)moe_down,
                        hipFuncAttributeMaxDynamicSharedMemorySize, RING_LDS);

    hipMemsetAsync(d_out, 0, (size_t)out_size * sizeof(float), stream);

    tcast3_kernel<<<dim3(32, 32, 24), 256, 0, stream>>>(gw, uw, dw, wgT, wuT, wdT);
    router_kernel<<<T, 64, 0, stream>>>(x, rw, rb, xb, top_i, top_w, T);
    bucket_kernel<<<1, 256, 0, stream>>>(top_i, top_w, meta, tos, wos, T);

    moe_gate_up<<<T256 * 32, 512, RING_LDS, stream>>>(xb, wgT, wuT, meta, tos, H);
    moe_down<<<T128 * 8, 512, RING_LDS, stream>>>(H, wdT, meta, tos, wos, out, S2);
}

// Round 13
// 300.222 us; speedup vs baseline: 1.0505x; 1.0505x over previous
//
#include <hip/hip_runtime.h>
#include <hip/hip_bf16.h>
#include <stdint.h>

#define D_MODEL 1024
#define D_INNER 2048
#define NEXP 8
#define TOPK 2
#define T256 40
#define T128 72

typedef float f32x4 __attribute__((ext_vector_type(4)));
typedef short bf16x8 __attribute__((ext_vector_type(8)));

#define VM0 asm volatile("s_waitcnt vmcnt(0)" ::: "memory")
#define VM6 asm volatile("s_waitcnt vmcnt(6)" ::: "memory")
#define BAR __builtin_amdgcn_s_barrier()

__device__ __forceinline__ unsigned short f2b(float f) {
    union { float f; uint32_t u; } v; v.f = f;
    uint32_t u = v.u;
    return (unsigned short)((u + 0x7fffu + ((u >> 16) & 1u)) >> 16);
}

__device__ __forceinline__ void gl_lds16(const void* g, void* l) {
    __builtin_amdgcn_global_load_lds((const __attribute__((address_space(1))) void*)g,
                                     (__attribute__((address_space(3))) void*)l, 16, 0, 0);
}

// ------- cast+transpose all 3 weights: [E][K][N] fp32 -> [E][N][K] bf16 -------
__global__ __launch_bounds__(256) void tcast3_kernel(
    const float* __restrict__ gw, const float* __restrict__ uw, const float* __restrict__ dw,
    unsigned short* __restrict__ gT, unsigned short* __restrict__ uT, unsigned short* __restrict__ dT)
{
    __shared__ unsigned short S[64][68];
    int which = blockIdx.z >> 3;
    int e = blockIdx.z & 7;
    const float* in; unsigned short* out; int K, N;
    if (which == 0)      { in = gw; out = gT; K = D_MODEL; N = D_INNER; }
    else if (which == 1) { in = uw; out = uT; K = D_MODEL; N = D_INNER; }
    else                 { in = dw; out = dT; K = D_INNER; N = D_MODEL; }
    int n0 = blockIdx.x * 64, k0 = blockIdx.y * 64;
    if (n0 >= N || k0 >= K) return;
    const float* ib = in + (size_t)e * K * N;
    unsigned short* ob = out + (size_t)e * N * K;
    int tid = threadIdx.x;
    int kk = tid >> 4, nn4 = (tid & 15) * 4;
#pragma unroll
    for (int j = 0; j < 4; j++) {
        int k = kk + 16 * j;
        float4 v = *(const float4*)&ib[(size_t)(k0 + k) * N + n0 + nn4];
        ushort4 s; s.x = f2b(v.x); s.y = f2b(v.y); s.z = f2b(v.z); s.w = f2b(v.w);
        *(ushort4*)&S[k][nn4] = s;
    }
    __syncthreads();
    int nn = tid >> 4, kk4 = (tid & 15) * 4;
#pragma unroll
    for (int j = 0; j < 4; j++) {
        int n = nn + 16 * j;
        ushort4 s;
        s.x = S[kk4 + 0][n]; s.y = S[kk4 + 1][n];
        s.z = S[kk4 + 2][n]; s.w = S[kk4 + 3][n];
        *(ushort4*)&ob[(size_t)(n0 + n) * K + k0 + kk4] = s;
    }
}

// ---------------- router (+ fused x->bf16 cast): 1 wave per token ----------------
__global__ __launch_bounds__(64) void router_kernel(
    const float* __restrict__ x, const float* __restrict__ rw,
    const float* __restrict__ rb, unsigned short* __restrict__ xb,
    int* __restrict__ top_i, float* __restrict__ top_w, int T)
{
    int t = blockIdx.x;
    if (t >= T) return;
    int l = threadIdx.x;
    float xv[16];
#pragma unroll
    for (int i = 0; i < 16; i++) xv[i] = x[(size_t)t * D_MODEL + l + 64 * i];
#pragma unroll
    for (int i = 0; i < 16; i++) xb[(size_t)t * D_MODEL + l + 64 * i] = f2b(xv[i]);
    float logit[NEXP];
#pragma unroll
    for (int e = 0; e < NEXP; e++) {
        float acc = 0.f;
#pragma unroll
        for (int i = 0; i < 16; i++) acc += xv[i] * rw[e * D_MODEL + l + 64 * i];
#pragma unroll
        for (int s = 32; s > 0; s >>= 1) acc += __shfl_xor(acc, s, 64);
        logit[e] = acc + rb[e];
    }
    if (l == 0) {
        int i0 = 0; float m0 = logit[0];
#pragma unroll
        for (int e = 1; e < NEXP; e++) if (logit[e] > m0) { m0 = logit[e]; i0 = e; }
        int i1 = -1; float m1 = -3.0e38f;
#pragma unroll
        for (int e = 0; e < NEXP; e++) {
            if (e == i0) continue;
            if (logit[e] > m1) { m1 = logit[e]; i1 = e; }
        }
        float w0 = 1.f / (1.f + expf(m1 - m0));
        top_i[t * 2 + 0] = i0; top_i[t * 2 + 1] = i1;
        top_w[t * 2 + 0] = w0; top_w[t * 2 + 1] = 1.f - w0;
    }
}

// ---------------- bucket build + compact tile worklists ----------------
__global__ __launch_bounds__(256) void bucket_kernel(
    const int* __restrict__ top_i, const float* __restrict__ top_w,
    int* __restrict__ meta, int* __restrict__ tok_of_slot,
    float* __restrict__ w_of_slot, int T)
{
    __shared__ int cnt[256][NEXP];
    __shared__ int pre[256][NEXP];
    __shared__ int tot[NEXP];
    __shared__ int off[NEXP + 1];
    int tid = threadIdx.x;
    int per = (T + 255) / 256;
    int t0 = tid * per;
    for (int e = 0; e < NEXP; e++) cnt[tid][e] = 0;
    for (int t = t0; t < t0 + per && t < T; t++)
        for (int k = 0; k < TOPK; k++) cnt[tid][top_i[t * 2 + k]]++;
    __syncthreads();
    if (tid < NEXP) {
        int run = 0;
        for (int i = 0; i < 256; i++) { pre[i][tid] = run; run += cnt[i][tid]; }
        tot[tid] = run;
    }
    __syncthreads();
    if (tid == 0) {
        off[0] = 0;
        for (int e = 0; e < NEXP; e++) off[e + 1] = off[e] + tot[e];
        for (int e = 0; e <= NEXP; e++) meta[e] = off[e];
        int nt = 0;
        for (int e = 0; e < NEXP; e++)
            for (int r = off[e]; r < off[e + 1]; r += 256)
                meta[16 + nt++] = (e << 16) | r;
        meta[11] = nt;
        for (; nt < T256; nt++) meta[16 + nt] = -1;
    }
    __syncthreads();
    int lc[NEXP];
#pragma unroll
    for (int e = 0; e < NEXP; e++) lc[e] = 0;
    for (int t = t0; t < t0 + per && t < T; t++) {
        for (int k = 0; k < TOPK; k++) {
            int e = top_i[t * 2 + k];
            int slot = off[e] + pre[tid][e] + lc[e]++;
            tok_of_slot[slot] = t;
            w_of_slot[slot] = top_w[t * 2 + k];
        }
    }
}

// ======================= gate+up GEMM + swiglu -> H =======================
// 512 thr / 8 waves (4M x 2sel). Tile M=256 x Bhat128 (g64+u64 stacked), BK=64.
// Per-wave 64x64 of ONE matrix (acc=64). 3-ring x 48KB LDS, 2-tile-deep prefetch,
// counted vmcnt(6) at each K-tile boundary (oldest outstanding = tile t+2's 6
// loads => t+1 proven landed, never drain). 2 phases/K-tile, 16-MFMA clusters,
// no sched_barrier / no explicit lgkm (compiler emits incremental lgkmcnt).
__global__ __launch_bounds__(512, 1) void moe_gate_up(
    const unsigned short* __restrict__ xb, const unsigned short* __restrict__ wgT,
    const unsigned short* __restrict__ wuT, const int* __restrict__ meta,
    const int* __restrict__ tok_of_slot, unsigned short* __restrict__ H)
{
    extern __shared__ __align__(16) unsigned short lds[];   // 3 * 24576 ushorts

    int lin = blockIdx.x;
    int strip = (lin & 7) * 4 + ((lin >> 3) & 3);   // lin%8 = XCD
    int tix = lin >> 5;
    int packed = meta[16 + tix];
    if (packed < 0) return;
    int e = packed >> 16, row0 = packed & 0xffff;
    int Mloc = min(256, meta[e + 1] - row0);
    int f0 = strip * 64;

    int tid = threadIdx.x, wv = tid >> 6, lane = tid & 63;
    int lrow = lane & 15, kgrp = lane >> 4, sw = lrow & 7;
    int wm = wv >> 1, sel = wv & 1;
    int co0 = 8 * (kgrp ^ sw);
    int co1 = 8 * ((4 + kgrp) ^ sw);

    // staging sources: A 4 calls (64 rows each), Bhat 2 calls (g, u)
    int srow = tid >> 3, schk = tid & 7;
    const unsigned short* sA[4];
#pragma unroll
    for (int j = 0; j < 4; j++) {
        int r = j * 64 + srow;
        int slot = row0 + ((r < Mloc) ? r : 0);
        sA[j] = xb + (size_t)tok_of_slot[slot] * D_MODEL + 8 * (schk ^ (r & 7));
    }
    const unsigned short *sG, *sU;
    {
        size_t wb = (size_t)e * D_MODEL * D_INNER + (size_t)(f0 + srow) * D_MODEL + 8 * (schk ^ (srow & 7));
        sG = wgT + wb; sU = wuT + wb;
    }
    int dst = tid * 8;

    int aoff[4], boff[4];
#pragma unroll
    for (int i = 0; i < 4; i++) aoff[i] = (wm * 64 + i * 16 + lrow) * 64;
#pragma unroll
    for (int i = 0; i < 4; i++) boff[i] = 16384 + (sel * 64 + i * 16 + lrow) * 64;

    f32x4 acc[4][4];
#pragma unroll
    for (int i = 0; i < 4; i++)
#pragma unroll
        for (int j = 0; j < 4; j++) acc[i][j] = (f32x4){0.f, 0.f, 0.f, 0.f};

    auto stageA = [&](int u) {   // 4 gl_lds: 32KB A
        int kk = u * 64; unsigned short* b = lds + (u % 3) * 24576;
        gl_lds16(sA[0] + kk, b + dst);
        gl_lds16(sA[1] + kk, b + 4096 + dst);
        gl_lds16(sA[2] + kk, b + 8192 + dst);
        gl_lds16(sA[3] + kk, b + 12288 + dst);
    };
    auto stageB = [&](int u) {   // 2 gl_lds: 16KB Bhat (g rows 0-63, u rows 64-127)
        int kk = u * 64; unsigned short* b = lds + (u % 3) * 24576;
        gl_lds16(sG + kk, b + 16384 + dst);
        gl_lds16(sU + kk, b + 20480 + dst);
    };

    const int NT = D_MODEL / 64;   // 16
    stageA(0); stageB(0); stageA(1); stageB(1);
    VM6; BAR;

    for (int t = 0; t < NT; ++t) {
        const unsigned short* b = lds + (t % 3) * 24576;
        bool pf = (t + 2) < NT;
        bf16x8 A[4][2], B[2][2];
        // ---- P0: reads A(8) + B fn0-1(4), stage A(t+2), 16 MFMA ----
#pragma unroll
        for (int i = 0; i < 4; i++) {
            A[i][0] = *(const bf16x8*)(b + aoff[i] + co0);
            A[i][1] = *(const bf16x8*)(b + aoff[i] + co1);
        }
#pragma unroll
        for (int j = 0; j < 2; j++) {
            B[j][0] = *(const bf16x8*)(b + boff[j] + co0);
            B[j][1] = *(const bf16x8*)(b + boff[j] + co1);
        }
        if (pf) stageA(t + 2);
        BAR;
        __builtin_amdgcn_s_setprio(1);
#pragma unroll
        for (int i = 0; i < 4; i++)
#pragma unroll
            for (int j = 0; j < 2; j++) {
                acc[i][j] = __builtin_amdgcn_mfma_f32_16x16x32_bf16(A[i][0], B[j][0], acc[i][j], 0, 0, 0);
                acc[i][j] = __builtin_amdgcn_mfma_f32_16x16x32_bf16(A[i][1], B[j][1], acc[i][j], 0, 0, 0);
            }
        __builtin_amdgcn_s_setprio(0);
        BAR;
        // ---- P1: reads B fn2-3(4), stage B(t+2), 16 MFMA, counted vmcnt ----
#pragma unroll
        for (int j = 0; j < 2; j++) {
            B[j][0] = *(const bf16x8*)(b + boff[2 + j] + co0);
            B[j][1] = *(const bf16x8*)(b + boff[2 + j] + co1);
        }
        if (pf) stageB(t + 2);
        BAR;
        __builtin_amdgcn_s_setprio(1);
#pragma unroll
        for (int i = 0; i < 4; i++)
#pragma unroll
            for (int j = 0; j < 2; j++) {
                acc[i][2 + j] = __builtin_amdgcn_mfma_f32_16x16x32_bf16(A[i][0], B[j][0], acc[i][2 + j], 0, 0, 0);
                acc[i][2 + j] = __builtin_amdgcn_mfma_f32_16x16x32_bf16(A[i][1], B[j][1], acc[i][2 + j], 0, 0, 0);
            }
        __builtin_amdgcn_s_setprio(0);
        if (pf) { VM6; } else { VM0; }
        BAR;
    }

    // epilogue: u-waves publish acc via LDS f32 [64][66] per wm (2-way banks);
    // g-waves fuse silu and store H.
    __syncthreads();
    float* ex = (float*)lds;
    if (sel == 1) {
        float* d = ex + wm * 4224;
#pragma unroll
        for (int i = 0; i < 4; i++)
#pragma unroll
            for (int j = 0; j < 4; j++)
#pragma unroll
                for (int r = 0; r < 4; r++)
                    d[(i * 16 + kgrp * 4 + r) * 66 + j * 16 + lrow] = acc[i][j][r];
    }
    __syncthreads();
    if (sel == 0) {
        const float* s = ex + wm * 4224;
#pragma unroll
        for (int i = 0; i < 4; i++)
#pragma unroll
            for (int j = 0; j < 4; j++)
#pragma unroll
                for (int r = 0; r < 4; r++) {
                    int row = i * 16 + kgrp * 4 + r;
                    int m = wm * 64 + row;
                    if (m < Mloc) {
                        float g = acc[i][j][r];
                        float u = s[row * 66 + j * 16 + lrow];
                        float h = g / (1.f + __expf(-g)) * u;
                        H[(size_t)(row0 + m) * D_INNER + f0 + j * 16 + lrow] = f2b(h);
                    }
                }
    }
}

// ======================= down GEMM + weighted scatter =======================
// Same structure: tile M=256 x N=128, BK=64, 8 waves (4M x 2N) of 64x64,
// 3-ring x 48KB, counted vmcnt(6), 2 phases/K-tile. NT=32. Atomic epilogue.
__global__ __launch_bounds__(512, 1) void moe_down(
    const unsigned short* __restrict__ H, const unsigned short* __restrict__ wdT,
    const int* __restrict__ meta, const int* __restrict__ tok_of_slot,
    const float* __restrict__ w_of_slot, float* __restrict__ out)
{
    extern __shared__ __align__(16) unsigned short lds[];   // 3 * 24576 ushorts
    __shared__ int toks[256];
    __shared__ float wts[256];

    int lin = blockIdx.x;
    int d0 = (lin & 7) * 128;      // lin%8 = XCD -> L2-resident wdT slice
    int tix = lin >> 3;
    int packed = meta[16 + tix];
    if (packed < 0) return;
    int e = packed >> 16, row0 = packed & 0xffff;
    int Mloc = min(256, meta[e + 1] - row0);

    int tid = threadIdx.x, wv = tid >> 6, lane = tid & 63;
    int lrow = lane & 15, kgrp = lane >> 4, sw = lrow & 7;
    int wm = wv >> 1, wn = wv & 1;
    int co0 = 8 * (kgrp ^ sw);
    int co1 = 8 * ((4 + kgrp) ^ sw);

    if (tid < 256) {
        bool v = tid < Mloc;
        toks[tid] = v ? tok_of_slot[row0 + tid] : 0;
        wts[tid] = v ? w_of_slot[row0 + tid] : 0.f;
    }

    int srow = tid >> 3, schk = tid & 7;
    const unsigned short* sA[4];
#pragma unroll
    for (int j = 0; j < 4; j++) {
        int r = j * 64 + srow;
        int slot = row0 + ((r < Mloc) ? r : 0);
        sA[j] = H + (size_t)slot * D_INNER + 8 * (schk ^ (r & 7));
    }
    const unsigned short* sB[2];
#pragma unroll
    for (int j = 0; j < 2; j++) {
        int r = j * 64 + srow;
        sB[j] = wdT + (size_t)e * D_INNER * D_MODEL + (size_t)(d0 + r) * D_INNER + 8 * (schk ^ (r & 7));
    }
    int dst = tid * 8;

    int aoff[4], boff[4];
#pragma unroll
    for (int i = 0; i < 4; i++) aoff[i] = (wm * 64 + i * 16 + lrow) * 64;
#pragma unroll
    for (int i = 0; i < 4; i++) boff[i] = 16384 + (wn * 64 + i * 16 + lrow) * 64;

    f32x4 acc[4][4];
#pragma unroll
    for (int i = 0; i < 4; i++)
#pragma unroll
        for (int j = 0; j < 4; j++) acc[i][j] = (f32x4){0.f, 0.f, 0.f, 0.f};

    auto stageA = [&](int u) {
        int kk = u * 64; unsigned short* b = lds + (u % 3) * 24576;
        gl_lds16(sA[0] + kk, b + dst);
        gl_lds16(sA[1] + kk, b + 4096 + dst);
        gl_lds16(sA[2] + kk, b + 8192 + dst);
        gl_lds16(sA[3] + kk, b + 12288 + dst);
    };
    auto stageB = [&](int u) {
        int kk = u * 64; unsigned short* b = lds + (u % 3) * 24576;
        gl_lds16(sB[0] + kk, b + 16384 + dst);
        gl_lds16(sB[1] + kk, b + 20480 + dst);
    };

    const int NT = D_INNER / 64;   // 32
    stageA(0); stageB(0); stageA(1); stageB(1);
    VM6; BAR;

    for (int t = 0; t < NT; ++t) {
        const unsigned short* b = lds + (t % 3) * 24576;
        bool pf = (t + 2) < NT;
        bf16x8 A[4][2], B[2][2];
#pragma unroll
        for (int i = 0; i < 4; i++) {
            A[i][0] = *(const bf16x8*)(b + aoff[i] + co0);
            A[i][1] = *(const bf16x8*)(b + aoff[i] + co1);
        }
#pragma unroll
        for (int j = 0; j < 2; j++) {
            B[j][0] = *(const bf16x8*)(b + boff[j] + co0);
            B[j][1] = *(const bf16x8*)(b + boff[j] + co1);
        }
        if (pf) stageA(t + 2);
        BAR;
        __builtin_amdgcn_s_setprio(1);
#pragma unroll
        for (int i = 0; i < 4; i++)
#pragma unroll
            for (int j = 0; j < 2; j++) {
                acc[i][j] = __builtin_amdgcn_mfma_f32_16x16x32_bf16(A[i][0], B[j][0], acc[i][j], 0, 0, 0);
                acc[i][j] = __builtin_amdgcn_mfma_f32_16x16x32_bf16(A[i][1], B[j][1], acc[i][j], 0, 0, 0);
            }
        __builtin_amdgcn_s_setprio(0);
        BAR;
#pragma unroll
        for (int j = 0; j < 2; j++) {
            B[j][0] = *(const bf16x8*)(b + boff[2 + j] + co0);
            B[j][1] = *(const bf16x8*)(b + boff[2 + j] + co1);
        }
        if (pf) stageB(t + 2);
        BAR;
        __builtin_amdgcn_s_setprio(1);
#pragma unroll
        for (int i = 0; i < 4; i++)
#pragma unroll
            for (int j = 0; j < 2; j++) {
                acc[i][2 + j] = __builtin_amdgcn_mfma_f32_16x16x32_bf16(A[i][0], B[j][0], acc[i][2 + j], 0, 0, 0);
                acc[i][2 + j] = __builtin_amdgcn_mfma_f32_16x16x32_bf16(A[i][1], B[j][1], acc[i][2 + j], 0, 0, 0);
            }
        __builtin_amdgcn_s_setprio(0);
        if (pf) { VM6; } else { VM0; }
        BAR;
    }

    // epilogue: weighted atomic scatter (2 commutative fp32 adds per out elem)
#pragma unroll
    for (int i = 0; i < 4; i++)
#pragma unroll
        for (int j = 0; j < 4; j++)
#pragma unroll
            for (int r = 0; r < 4; r++) {
                int m = wm * 64 + i * 16 + kgrp * 4 + r;
                if (m < Mloc) {
                    int n = d0 + wn * 64 + j * 16 + lrow;
                    atomicAdd(&out[(size_t)toks[m] * D_MODEL + n], wts[m] * acc[i][j][r]);
                }
            }
}

extern "C" void kernel_launch(void* const* d_in, const int* in_sizes, int n_in,
                              void* d_out, int out_size, void* d_ws, size_t ws_size,
                              hipStream_t stream) {
    const float* x  = (const float*)d_in[0];
    const float* rw = (const float*)d_in[1];
    const float* rb = (const float*)d_in[2];
    const float* gw = (const float*)d_in[3];
    const float* uw = (const float*)d_in[4];
    const float* dw = (const float*)d_in[5];
    float* out = (float*)d_out;

    int T = in_sizes[0] / D_MODEL;   // 4096
    int S2 = 2 * T;                   // 8192 slots

    char* ws = (char*)d_ws;
    size_t cur = 0;
    auto take = [&](size_t bytes) { char* p = ws + cur; cur = (cur + bytes + 255) & ~(size_t)255; return p; };
    int*   top_i = (int*)take((size_t)S2 * 4);
    float* top_w = (float*)take((size_t)S2 * 4);
    int*   meta  = (int*)take(1024);
    int*   tos   = (int*)take((size_t)S2 * 4);
    float* wos   = (float*)take((size_t)S2 * 4);
    unsigned short* xb  = (unsigned short*)take((size_t)T * D_MODEL * 2);
    unsigned short* wgT = (unsigned short*)take((size_t)NEXP * D_MODEL * D_INNER * 2);
    unsigned short* wuT = (unsigned short*)take((size_t)NEXP * D_MODEL * D_INNER * 2);
    unsigned short* wdT = (unsigned short*)take((size_t)NEXP * D_MODEL * D_INNER * 2);
    unsigned short* H   = (unsigned short*)take((size_t)S2 * D_INNER * 2);

    static const int RING_LDS = 3 * 24576 * 2;   // 147456 B
    hipFuncSetAttribute((const void*)moe_gate_up,
                        hipFuncAttributeMaxDynamicSharedMemorySize, RING_LDS);
    hipFuncSetAttribute((const void*)moe_down,
                        hipFuncAttributeMaxDynamicSharedMemorySize, RING_LDS);

    hipMemsetAsync(d_out, 0, (size_t)out_size * sizeof(float), stream);

    tcast3_kernel<<<dim3(32, 32, 24), 256, 0, stream>>>(gw, uw, dw, wgT, wuT, wdT);
    router_kernel<<<T, 64, 0, stream>>>(x, rw, rb, xb, top_i, top_w, T);
    bucket_kernel<<<1, 256, 0, stream>>>(top_i, top_w, meta, tos, wos, T);

    moe_gate_up<<<T256 * 32, 512, RING_LDS, stream>>>(xb, wgT, wuT, meta, tos, H);
    moe_down<<<T256 * 8, 512, RING_LDS, stream>>>(H, wdT, meta, tos, wos, out);
}

// Round 14
// 269.199 us; speedup vs baseline: 1.1715x; 1.1152x over previous
//
#include <hip/hip_runtime.h>
#include <hip/hip_bf16.h>
#include <stdint.h>

#define D_MODEL 1024
#define D_INNER 2048
#define NEXP 8
#define TOPK 2
#define BM 128
#define MAXT 72   // max M-tiles: floor(8192/128) + (NEXP-1) = 71, padded

typedef float f32x4 __attribute__((ext_vector_type(4)));
typedef short bf16x8 __attribute__((ext_vector_type(8)));

#define MEMFENCE asm volatile("" ::: "memory")

__device__ __forceinline__ unsigned short f2b(float f) {
    union { float f; uint32_t u; } v; v.f = f;
    uint32_t u = v.u;
    return (unsigned short)((u + 0x7fffu + ((u >> 16) & 1u)) >> 16);
}

__device__ __forceinline__ void gl_lds16(const void* g, void* l) {
    __builtin_amdgcn_global_load_lds((const __attribute__((address_space(1))) void*)g,
                                     (__attribute__((address_space(3))) void*)l, 16, 0, 0);
}

// ------- cast+transpose all 3 weights: [E][K][N] fp32 -> [E][N][K] bf16 -------
// x4 k-blocked: each block transposes four 64x64 tiles (fewer, fatter blocks).
__global__ __launch_bounds__(256) void tcast3_kernel(
    const float* __restrict__ gw, const float* __restrict__ uw, const float* __restrict__ dw,
    unsigned short* __restrict__ gT, unsigned short* __restrict__ uT, unsigned short* __restrict__ dT)
{
    __shared__ unsigned short S[64][68];
    int which = blockIdx.z >> 3;
    int e = blockIdx.z & 7;
    const float* in; unsigned short* out; int K, N;
    if (which == 0)      { in = gw; out = gT; K = D_MODEL; N = D_INNER; }
    else if (which == 1) { in = uw; out = uT; K = D_MODEL; N = D_INNER; }
    else                 { in = dw; out = dT; K = D_INNER; N = D_MODEL; }
    int n0 = blockIdx.x * 64;
    if (n0 >= N) return;
    const float* ib = in + (size_t)e * K * N;
    unsigned short* ob = out + (size_t)e * N * K;
    int tid = threadIdx.x;
    int kk = tid >> 4, nn4 = (tid & 15) * 4;
    int nn = tid >> 4, kk4 = (tid & 15) * 4;
    for (int kt = 0; kt < 4; ++kt) {
        int k0 = (blockIdx.y * 4 + kt) * 64;
        if (k0 >= K) break;
#pragma unroll
        for (int j = 0; j < 4; j++) {
            int k = kk + 16 * j;
            float4 v = *(const float4*)&ib[(size_t)(k0 + k) * N + n0 + nn4];
            ushort4 s; s.x = f2b(v.x); s.y = f2b(v.y); s.z = f2b(v.z); s.w = f2b(v.w);
            *(ushort4*)&S[k][nn4] = s;
        }
        __syncthreads();
#pragma unroll
        for (int j = 0; j < 4; j++) {
            int n = nn + 16 * j;
            ushort4 s;
            s.x = S[kk4 + 0][n]; s.y = S[kk4 + 1][n];
            s.z = S[kk4 + 2][n]; s.w = S[kk4 + 3][n];
            *(ushort4*)&ob[(size_t)(n0 + n) * K + k0 + kk4] = s;
        }
        __syncthreads();
    }
}

// ------- router (+ fused x->bf16 cast): 4 tokens per 256-thr block, 1 wave/token -------
__global__ __launch_bounds__(256) void router_kernel(
    const float* __restrict__ x, const float* __restrict__ rw,
    const float* __restrict__ rb, unsigned short* __restrict__ xb,
    int* __restrict__ top_i, float* __restrict__ top_w, int T)
{
    int t = blockIdx.x * 4 + (threadIdx.x >> 6);
    if (t >= T) return;
    int l = threadIdx.x & 63;
    float xv[16];
#pragma unroll
    for (int i = 0; i < 16; i++) xv[i] = x[(size_t)t * D_MODEL + l + 64 * i];
#pragma unroll
    for (int i = 0; i < 16; i++) xb[(size_t)t * D_MODEL + l + 64 * i] = f2b(xv[i]);
    float logit[NEXP];
#pragma unroll
    for (int e = 0; e < NEXP; e++) {
        float acc = 0.f;
#pragma unroll
        for (int i = 0; i < 16; i++) acc += xv[i] * rw[e * D_MODEL + l + 64 * i];
#pragma unroll
        for (int s = 32; s > 0; s >>= 1) acc += __shfl_xor(acc, s, 64);
        logit[e] = acc + rb[e];
    }
    if (l == 0) {
        int i0 = 0; float m0 = logit[0];
#pragma unroll
        for (int e = 1; e < NEXP; e++) if (logit[e] > m0) { m0 = logit[e]; i0 = e; }
        int i1 = -1; float m1 = -3.0e38f;
#pragma unroll
        for (int e = 0; e < NEXP; e++) {
            if (e == i0) continue;
            if (logit[e] > m1) { m1 = logit[e]; i1 = e; }
        }
        float w0 = 1.f / (1.f + expf(m1 - m0));
        top_i[t * 2 + 0] = i0; top_i[t * 2 + 1] = i1;
        top_w[t * 2 + 0] = w0; top_w[t * 2 + 1] = 1.f - w0;
    }
}

// ---------------- bucket build + compact tile worklist: 1 block ----------------
__global__ __launch_bounds__(256) void bucket_kernel(
    const int* __restrict__ top_i, const float* __restrict__ top_w,
    int* __restrict__ meta, int* __restrict__ tok_of_slot,
    float* __restrict__ w_of_slot, int T)
{
    __shared__ int cnt[256][NEXP];
    __shared__ int pre[256][NEXP];
    __shared__ int tot[NEXP];
    __shared__ int off[NEXP + 1];
    int tid = threadIdx.x;
    int per = (T + 255) / 256;
    int t0 = tid * per;
    for (int e = 0; e < NEXP; e++) cnt[tid][e] = 0;
    for (int t = t0; t < t0 + per && t < T; t++)
        for (int k = 0; k < TOPK; k++) cnt[tid][top_i[t * 2 + k]]++;
    __syncthreads();
    if (tid < NEXP) {
        int run = 0;
        for (int i = 0; i < 256; i++) { pre[i][tid] = run; run += cnt[i][tid]; }
        tot[tid] = run;
    }
    __syncthreads();
    if (tid == 0) {
        off[0] = 0;
        for (int e = 0; e < NEXP; e++) off[e + 1] = off[e] + tot[e];
        for (int e = 0; e <= NEXP; e++) meta[e] = off[e];
        int nt = 0;
        for (int e = 0; e < NEXP; e++)
            for (int r = off[e]; r < off[e + 1]; r += BM)
                meta[16 + nt++] = (e << 16) | r;
        for (; nt < MAXT; nt++) meta[16 + nt] = -1;
    }
    __syncthreads();
    int lc[NEXP];
#pragma unroll
    for (int e = 0; e < NEXP; e++) lc[e] = 0;
    for (int t = t0; t < t0 + per && t < T; t++) {
        for (int k = 0; k < TOPK; k++) {
            int e = top_i[t * 2 + k];
            int slot = off[e] + pre[tid][e] + lc[e]++;
            tok_of_slot[slot] = t;
            w_of_slot[slot] = top_w[t * 2 + k];
        }
    }
}

// ---------------- gate+up GEMM + swiglu -> H (r6-verbatim) ----------------
// MFMA-first schedule: per iter {MFMA(frags t) -> stage(t+2) -> counted vmcnt ->
// ONE barrier -> ds_read frags(t+1)}. Frag reads get a full iteration to land.
__global__ __launch_bounds__(256, 2) void moe_gate_up(
    const unsigned short* __restrict__ xb, const unsigned short* __restrict__ wgT,
    const unsigned short* __restrict__ wuT, const int* __restrict__ meta,
    const int* __restrict__ tok_of_slot, unsigned short* __restrict__ H)
{
    extern __shared__ __align__(16) unsigned short lds[];   // 3 * 12288 ushorts

    int lin = blockIdx.x;
    int strip = (lin & 7) * 2 + ((lin >> 3) & 1);   // lin%8 = XCD -> strip pair
    int tix = lin >> 4;
    int packed = meta[16 + tix];
    if (packed < 0) return;
    int e = packed >> 16, row0 = packed & 0xffff;
    int Mloc = min(BM, meta[e + 1] - row0);
    int f0 = strip * 128;

    int tid = threadIdx.x, wv = tid >> 6, lane = tid & 63;

    const unsigned short* srcA[2];
    const unsigned short* srcG[2];
    const unsigned short* srcU[2];
#pragma unroll
    for (int j = 0; j < 2; j++) {
        int row = j * 64 + (tid >> 2);
        int p = tid & 3;
        int koffA = 8 * (p ^ ((row >> 1) & 3));
        int slot = row0 + ((row < Mloc) ? row : 0);
        srcA[j] = xb + (size_t)tok_of_slot[slot] * D_MODEL + koffA;
        size_t wb = (size_t)e * D_MODEL * D_INNER + (size_t)(f0 + row) * D_MODEL + koffA;
        srcG[j] = wgT + wb;
        srcU[j] = wuT + wb;
    }

    int wm = wv >> 1, wn = wv & 1;
    int lrow = lane & 15, kgrp = lane >> 4;
    int co = 8 * (kgrp ^ ((lrow >> 1) & 3));

    int arow[4], brow[4];
#pragma unroll
    for (int fm = 0; fm < 4; fm++) arow[fm] = (wm * 64 + fm * 16 + lrow) * 32;
#pragma unroll
    for (int fn = 0; fn < 4; fn++) brow[fn] = (wn * 64 + fn * 16 + lrow) * 32;

    f32x4 accg[4][4], accu[4][4];
#pragma unroll
    for (int i = 0; i < 4; i++)
#pragma unroll
        for (int j = 0; j < 4; j++) {
            accg[i][j] = (f32x4){0.f, 0.f, 0.f, 0.f};
            accu[i][j] = (f32x4){0.f, 0.f, 0.f, 0.f};
        }

    auto stage = [&](int u) {
        int kk = u * 32;
        unsigned short* base = lds + (u % 3) * 12288;
#pragma unroll
        for (int j = 0; j < 2; j++) {
            int d = (j * 256 + wv * 64) * 8;
            gl_lds16(srcA[j] + kk, base + d);
            gl_lds16(srcG[j] + kk, base + 4096 + d);
            gl_lds16(srcU[j] + kk, base + 8192 + d);
        }
    };

    bf16x8 a[4], bg[4], bu[4];
    auto load_frags = [&](int u) {
        const unsigned short* base = lds + (u % 3) * 12288;
#pragma unroll
        for (int fm = 0; fm < 4; fm++) a[fm] = *(const bf16x8*)(base + arow[fm] + co);
#pragma unroll
        for (int fn = 0; fn < 4; fn++) {
            bg[fn] = *(const bf16x8*)(base + 4096 + brow[fn] + co);
            bu[fn] = *(const bf16x8*)(base + 8192 + brow[fn] + co);
        }
    };

    const int NT = D_MODEL / 32;   // 32
    stage(0); stage(1);
    MEMFENCE;
    asm volatile("s_waitcnt vmcnt(6)" ::: "memory");   // tile 0 landed
    __builtin_amdgcn_s_barrier();
    MEMFENCE;
    load_frags(0);

    for (int t = 0; t < NT; ++t) {
        __builtin_amdgcn_sched_barrier(0);
        __builtin_amdgcn_s_setprio(1);
#pragma unroll
        for (int fm = 0; fm < 4; fm++)
#pragma unroll
            for (int fn = 0; fn < 4; fn++) {
                accg[fm][fn] = __builtin_amdgcn_mfma_f32_16x16x32_bf16(a[fm], bg[fn], accg[fm][fn], 0, 0, 0);
                accu[fm][fn] = __builtin_amdgcn_mfma_f32_16x16x32_bf16(a[fm], bu[fn], accu[fm][fn], 0, 0, 0);
            }
        __builtin_amdgcn_s_setprio(0);
        __builtin_amdgcn_sched_barrier(0);

        if (t + 2 < NT) {
            stage(t + 2);
            asm volatile("s_waitcnt vmcnt(6)" ::: "memory");   // tile t+1 landed (mine)
        } else if (t + 1 < NT) {
            asm volatile("s_waitcnt vmcnt(0)" ::: "memory");
        }
        __builtin_amdgcn_s_barrier();
        MEMFENCE;
        if (t + 1 < NT) load_frags(t + 1);
    }

#pragma unroll
    for (int fm = 0; fm < 4; fm++)
#pragma unroll
        for (int fn = 0; fn < 4; fn++)
#pragma unroll
            for (int r = 0; r < 4; r++) {
                int m = wm * 64 + fm * 16 + kgrp * 4 + r;
                if (m < Mloc) {
                    int n = wn * 64 + fn * 16 + lrow;
                    float g = accg[fm][fn][r], u = accu[fm][fn][r];
                    float h = g / (1.f + __expf(-g)) * u;
                    H[(size_t)(row0 + m) * D_INNER + f0 + n] = f2b(h);
                }
            }
}

// ---------------- down GEMM + weighted scatter (r6-verbatim) ----------------
__global__ __launch_bounds__(256, 2) void moe_down(
    const unsigned short* __restrict__ H, const unsigned short* __restrict__ wdT,
    const int* __restrict__ meta, const int* __restrict__ tok_of_slot,
    const float* __restrict__ w_of_slot, float* __restrict__ out, int S2)
{
    __shared__ unsigned short lds[3 * 8192];
    __shared__ int toks[BM];
    __shared__ float wts[BM];

    int lin = blockIdx.x;
    int d0 = (lin & 7) * 128;
    int tix = lin >> 3;
    int packed = meta[16 + tix];
    if (packed < 0) return;
    int e = packed >> 16, row0 = packed & 0xffff;
    int Mloc = min(BM, meta[e + 1] - row0);

    int tid = threadIdx.x, wv = tid >> 6, lane = tid & 63;
    if (tid < BM) {
        bool v = tid < Mloc;
        toks[tid] = v ? tok_of_slot[row0 + tid] : 0;
        wts[tid] = v ? w_of_slot[row0 + tid] : 0.f;
    }

    const unsigned short* srcA[2];
    const unsigned short* srcB[2];
#pragma unroll
    for (int j = 0; j < 2; j++) {
        int row = j * 64 + (tid >> 2);
        int p = tid & 3;
        int koff = 8 * (p ^ ((row >> 1) & 3));
        int slot = min(row0 + row, S2 - 1);
        srcA[j] = H + (size_t)slot * D_INNER + koff;
        srcB[j] = wdT + (size_t)e * D_INNER * D_MODEL + (size_t)(d0 + row) * D_INNER + koff;
    }

    int wm = wv >> 1, wn = wv & 1;
    int lrow = lane & 15, kgrp = lane >> 4;
    int co = 8 * (kgrp ^ ((lrow >> 1) & 3));

    int arow[4], brow[4];
#pragma unroll
    for (int fm = 0; fm < 4; fm++) arow[fm] = (wm * 64 + fm * 16 + lrow) * 32;
#pragma unroll
    for (int fn = 0; fn < 4; fn++) brow[fn] = (wn * 64 + fn * 16 + lrow) * 32;

    f32x4 acc[4][4];
#pragma unroll
    for (int i = 0; i < 4; i++)
#pragma unroll
        for (int j = 0; j < 4; j++) acc[i][j] = (f32x4){0.f, 0.f, 0.f, 0.f};

    auto stage = [&](int u) {
        int kk = u * 32;
        unsigned short* base = lds + (u % 3) * 8192;
#pragma unroll
        for (int j = 0; j < 2; j++) {
            int d = (j * 256 + wv * 64) * 8;
            gl_lds16(srcA[j] + kk, base + d);
            gl_lds16(srcB[j] + kk, base + 4096 + d);
        }
    };

    bf16x8 a[4], b[4];
    auto load_frags = [&](int u) {
        const unsigned short* base = lds + (u % 3) * 8192;
#pragma unroll
        for (int fm = 0; fm < 4; fm++) a[fm] = *(const bf16x8*)(base + arow[fm] + co);
#pragma unroll
        for (int fn = 0; fn < 4; fn++) b[fn] = *(const bf16x8*)(base + 4096 + brow[fn] + co);
    };

    const int NT = D_INNER / 32;   // 64
    stage(0); stage(1);
    MEMFENCE;
    asm volatile("s_waitcnt vmcnt(4)" ::: "memory");
    __builtin_amdgcn_s_barrier();
    MEMFENCE;
    load_frags(0);

    for (int t = 0; t < NT; ++t) {
        __builtin_amdgcn_sched_barrier(0);
        __builtin_amdgcn_s_setprio(1);
#pragma unroll
        for (int fm = 0; fm < 4; fm++)
#pragma unroll
            for (int fn = 0; fn < 4; fn++)
                acc[fm][fn] = __builtin_amdgcn_mfma_f32_16x16x32_bf16(a[fm], b[fn], acc[fm][fn], 0, 0, 0);
        __builtin_amdgcn_s_setprio(0);
        __builtin_amdgcn_sched_barrier(0);

        if (t + 2 < NT) {
            stage(t + 2);
            asm volatile("s_waitcnt vmcnt(4)" ::: "memory");
        } else if (t + 1 < NT) {
            asm volatile("s_waitcnt vmcnt(0)" ::: "memory");
        }
        __builtin_amdgcn_s_barrier();
        MEMFENCE;
        if (t + 1 < NT) load_frags(t + 1);
    }

#pragma unroll
    for (int fm = 0; fm < 4; fm++)
#pragma unroll
        for (int fn = 0; fn < 4; fn++)
#pragma unroll
            for (int r = 0; r < 4; r++) {
                int m = wm * 64 + fm * 16 + kgrp * 4 + r;
                if (m < Mloc) {
                    int n = d0 + wn * 64 + fn * 16 + lrow;
                    atomicAdd(&out[(size_t)toks[m] * D_MODEL + n], wts[m] * acc[fm][fn][r]);
                }
            }
}

extern "C" void kernel_launch(void* const* d_in, const int* in_sizes, int n_in,
                              void* d_out, int out_size, void* d_ws, size_t ws_size,
                              hipStream_t stream) {
    const float* x  = (const float*)d_in[0];
    const float* rw = (const float*)d_in[1];
    const float* rb = (const float*)d_in[2];
    const float* gw = (const float*)d_in[3];
    const float* uw = (const float*)d_in[4];
    const float* dw = (const float*)d_in[5];
    float* out = (float*)d_out;

    int T = in_sizes[0] / D_MODEL;   // 4096
    int S2 = 2 * T;                   // 8192 slots

    char* ws = (char*)d_ws;
    size_t cur = 0;
    auto take = [&](size_t bytes) { char* p = ws + cur; cur = (cur + bytes + 255) & ~(size_t)255; return p; };
    int*   top_i = (int*)take((size_t)S2 * 4);
    float* top_w = (float*)take((size_t)S2 * 4);
    int*   meta  = (int*)take(1024);
    int*   tos   = (int*)take((size_t)S2 * 4);
    float* wos   = (float*)take((size_t)S2 * 4);
    unsigned short* xb  = (unsigned short*)take((size_t)T * D_MODEL * 2);
    unsigned short* wgT = (unsigned short*)take((size_t)NEXP * D_MODEL * D_INNER * 2);
    unsigned short* wuT = (unsigned short*)take((size_t)NEXP * D_MODEL * D_INNER * 2);
    unsigned short* wdT = (unsigned short*)take((size_t)NEXP * D_MODEL * D_INNER * 2);
    unsigned short* H   = (unsigned short*)take((size_t)S2 * D_INNER * 2);

    static const int GU_LDS = 3 * 12288 * 2;   // 73728 B dynamic LDS
    hipFuncSetAttribute((const void*)moe_gate_up,
                        hipFuncAttributeMaxDynamicSharedMemorySize, GU_LDS);

    hipMemsetAsync(d_out, 0, (size_t)out_size * sizeof(float), stream);

    // prep: fatter blocks (tcast3: 4 k-tiles/block; router: 4 tokens/block)
    tcast3_kernel<<<dim3(32, 8, 24), 256, 0, stream>>>(gw, uw, dw, wgT, wuT, wdT);
    router_kernel<<<(T + 3) / 4, 256, 0, stream>>>(x, rw, rb, xb, top_i, top_w, T);
    bucket_kernel<<<1, 256, 0, stream>>>(top_i, top_w, meta, tos, wos, T);

    moe_gate_up<<<MAXT * 16, 256, GU_LDS, stream>>>(xb, wgT, wuT, meta, tos, H);
    moe_down<<<MAXT * 8, 256, 0, stream>>>(H, wdT, meta, tos, wos, out, S2);
}